// Round 11
// baseline (448.825 us; speedup 1.0000x reference)
//
#include <hip/hip_runtime.h>
#include <hip/hip_fp16.h>

#define NPOI 50000
#define EMB 128
#define NEDGE 800000
#define EAUG (2 * NEDGE + NPOI)
#define BATCH 512
#define SEQL 64
#define NHEADS 4
#define HDIM 32
#define NB 196                              // 256-node buckets
#define P1_BLOCKS ((NEDGE + 2047) / 2048)   // 391
#define SLAB_CAP 10240
#define BUCKET_CAP 10240

typedef _Float16 half8 __attribute__((ext_vector_type(8)));
typedef _Float16 half4 __attribute__((ext_vector_type(4)));
typedef _Float16 half2t __attribute__((ext_vector_type(2)));
typedef float f32x4 __attribute__((ext_vector_type(4)));
typedef unsigned long long u64;

union HBits { _Float16 h; unsigned short u; };

// ---------------- fused fp32 -> fp16 convert (poi, lin_w, in_proj_w) + bcur init ----------------

#define N4_POI (NPOI * 128 / 4)
#define N4_LIN (2 * 128 * 128 / 4)
#define N4_INW (384 * 128 / 4)
#define CVT_TOT (N4_POI + N4_LIN + N4_INW + NB)

__global__ void cvt_all_kernel(const float* __restrict__ poi, const float* __restrict__ linw,
                               const float* __restrict__ inw,
                               _Float16* __restrict__ poi_h, _Float16* __restrict__ linw_h,
                               _Float16* __restrict__ inw_h, int* __restrict__ bcur) {
    int i = blockIdx.x * blockDim.x + threadIdx.x;
    const float* src; _Float16* dst; int j = i;
    if (i < N4_POI) { src = poi; dst = poi_h; }
    else if (i < N4_POI + N4_LIN) { j = i - N4_POI; src = linw; dst = linw_h; }
    else if (i < N4_POI + N4_LIN + N4_INW) { j = i - N4_POI - N4_LIN; src = inw; dst = inw_h; }
    else if (i < CVT_TOT) { int b = i - (N4_POI + N4_LIN + N4_INW); bcur[b] = b * SLAB_CAP; return; }
    else return;
    float4 v = ((const float4*)src)[j];
    half4 h = { (_Float16)v.x, (_Float16)v.y, (_Float16)v.z, (_Float16)v.w };
    ((half4*)dst)[j] = h;
}

// ---------------- phase 1: LDS-buffered multisplit into static per-bucket slabs ----------------

__global__ __launch_bounds__(256) void partition_kernel(
    const int* __restrict__ e0, const int* __restrict__ e1,
    const float* __restrict__ dv, int* __restrict__ bcur,
    u64* __restrict__ staging)
{
    __shared__ u64 stg[4096];
    __shared__ int lh[NB], lbase[NB], gb[NB];
    __shared__ int sc[256];
    const int t = threadIdx.x;
    const int blockBase = blockIdx.x * 2048;
    for (int j = t; j < NB; j += 256) lh[j] = 0;
    __syncthreads();

    u64 vals[16];
    unsigned br[16];
#pragma unroll
    for (int i = 0; i < 8; ++i) {
        br[2 * i] = 0xFFFFFFFFu;
        br[2 * i + 1] = 0xFFFFFFFFu;
        int g = blockBase + i * 256 + t;
        if (g < NEDGE) {
            int s = e0[g], d = e1[g];
            unsigned db = __float_as_uint(dv[g]);
            vals[2 * i]     = ((u64)s << 48) | ((u64)d << 32) | db;
            vals[2 * i + 1] = ((u64)d << 48) | ((u64)s << 32) | db;
            int bs = s >> 8, bd = d >> 8;
            int rs = atomicAdd(&lh[bs], 1);
            int rd_ = atomicAdd(&lh[bd], 1);
            br[2 * i]     = ((unsigned)bs << 16) | (unsigned)rs;
            br[2 * i + 1] = ((unsigned)bd << 16) | (unsigned)rd_;
        }
    }
    __syncthreads();
    sc[t] = (t < NB) ? lh[t] : 0;
    __syncthreads();
    for (int o = 1; o < 256; o <<= 1) {
        int u = (t >= o) ? sc[t - o] : 0;
        __syncthreads();
        sc[t] += u;
        __syncthreads();
    }
    if (t < NB) {
        lbase[t] = sc[t] - lh[t];
        gb[t] = (lh[t] > 0) ? atomicAdd(&bcur[t], lh[t]) : 0;
    }
    __syncthreads();
#pragma unroll
    for (int i = 0; i < 16; ++i) {
        if (br[i] != 0xFFFFFFFFu) {
            int b = br[i] >> 16, r = br[i] & 0xFFFF;
            stg[lbase[b] + r] = vals[i];
        }
    }
    __syncthreads();
    const int total = sc[255];
    for (int j = t; j < total; j += 256) {
        u64 v = stg[j];
        int b = (int)(v >> 56);
        staging[(size_t)gb[b] + (unsigned)(j - lbase[b])] = v;
    }
}

// ---------------- per-bucket histogram -> rd = rsqrt(deg), bsum ----------------

__global__ __launch_bounds__(256) void hist_kernel(const u64* __restrict__ staging,
                                                   const int* __restrict__ bcur,
                                                   float* __restrict__ rd,
                                                   int* __restrict__ bsum) {
    __shared__ int cnt[256];
    __shared__ int red[256];
    const int b = blockIdx.x, t = threadIdx.x;
    cnt[t] = 0;
    __syncthreads();
    const int base = b * SLAB_CAP;
    const int n = bcur[b] - base;
    for (int j = t; j < n; j += 256)
        atomicAdd(&cnt[(int)(staging[base + j] >> 48) & 255], 1);
    __syncthreads();
    int node = b * 256 + t;
    int rowsz = 0;
    if (node < NPOI) {
        rowsz = cnt[t] + 1;   // + self loop
        rd[node] = rsqrtf((float)rowsz);
    }
    red[t] = rowsz;
    __syncthreads();
    for (int o = 128; o > 0; o >>= 1) {
        if (t < o) red[t] += red[t + o];
        __syncthreads();
    }
    if (t == 0) bsum[b] = red[0];
}

// ---------------- phase 2: per-bucket counting sort + weights + offs -> packed CSR ----------------

__global__ __launch_bounds__(256) void csr_sort_kernel(
    const u64* __restrict__ staging, const int* __restrict__ bcur,
    const int* __restrict__ bsum, const float* __restrict__ rd,
    int* __restrict__ offs, unsigned* __restrict__ ew)
{
    const int k = blockIdx.x;
    const int node0 = k * 256;
    __shared__ unsigned outb[BUCKET_CAP];
    __shared__ int cnt[256], base2[256];
    __shared__ float rdl[256];
    __shared__ int bb_sh;
    const int t = threadIdx.x;
    const int node = node0 + t;
    cnt[t] = 0;
    rdl[t] = (node < NPOI) ? rd[node] : 0.f;
    // bucket base = prefix sum of bsum[0..k-1]
    {
        int partial = 0;
        for (int j = t; j < k; j += 256) partial += bsum[j];
        base2[t] = partial;
        __syncthreads();
        for (int o = 128; o > 0; o >>= 1) {
            if (t < o) base2[t] += base2[t + o];
            __syncthreads();
        }
        if (t == 0) bb_sh = base2[0];
        __syncthreads();
    }
    const int bucketbase = bb_sh;
    __syncthreads();
    const int sb = k * SLAB_CAP;
    const int n = bcur[k] - sb;
    for (int j = t; j < n; j += 256)
        atomicAdd(&cnt[(int)(staging[sb + j] >> 48) & 255], 1);
    __syncthreads();
    int rowsz = (node < NPOI) ? cnt[t] + 1 : 0;
    base2[t] = rowsz;
    __syncthreads();
    for (int o = 1; o < 256; o <<= 1) {
        int u = (t >= o) ? base2[t - o] : 0;
        __syncthreads();
        base2[t] += u;
        __syncthreads();
    }
    int myexc = base2[t] - rowsz;
    __syncthreads();
    base2[t] = myexc;
    cnt[t] = 0;
    if (node < NPOI) {
        offs[node] = bucketbase + myexc;
        if (node == NPOI - 1) offs[NPOI] = bucketbase + myexc + rowsz;
    }
    __syncthreads();
    for (int j = t; j < n; j += 256) {
        u64 e = staging[sb + j];
        int sl = (int)(e >> 48) & 255;
        int d = (int)(e >> 32) & 0xFFFF;
        float dist = __uint_as_float((unsigned)e);
        float w = rdl[sl] * rd[d] * expf(-dist * dist);
        HBits cv; cv.h = (_Float16)w;
        int r = atomicAdd(&cnt[sl], 1);
        outb[base2[sl] + r] = ((unsigned)d << 16) | cv.u;
    }
    __syncthreads();
    if (node < NPOI) {   // self loop in last slot of the row
        float w = rdl[t] * rdl[t];
        HBits cv; cv.h = (_Float16)w;
        outb[base2[t] + cnt[t]] = ((unsigned)node << 16) | cv.u;
    }
    __syncthreads();
    const int ntot = (node0 + 256 < NPOI ? n + 256 : n + (NPOI - node0));
    for (int j = t; j < ntot; j += 256) ew[bucketbase + j] = outb[j];   // coalesced
}

// ---------------- fp16 MFMA GEMM: C[M,N] = diag(ns)·A(gathered)[M,128] @ B[N,128]^T + bias ----
// ns (nullable): per-A-row scale applied before bias (linearity: row norm factored out)

__global__ __launch_bounds__(256) void gemm_mfma_f16(
    const _Float16* __restrict__ A, const int* __restrict__ gidx,
    const float* __restrict__ ns,
    const _Float16* __restrict__ B, const float* __restrict__ bias,
    _Float16* __restrict__ C, int M, int N)
{
    __shared__ _Float16 Asl[64][136];
    __shared__ _Float16 Bsl[64][136];
    const int tid = threadIdx.x;
    const int n0 = blockIdx.x * 64;
    const int m0 = blockIdx.y * 64;

#pragma unroll
    for (int i = 0; i < 4; ++i) {
        int u = i * 256 + tid;
        int r = u >> 4;
        int c = u & 15;
        int row = m0 + r;
        int ar = (row < M) ? (gidx ? gidx[row] : row) : 0;
        *(float4*)&Asl[r][c * 8] = *(const float4*)(A + (size_t)ar * 128 + c * 8);
        *(float4*)&Bsl[r][c * 8] = *(const float4*)(B + (size_t)(n0 + r) * 128 + c * 8);
    }
    __syncthreads();

    const int wave = tid >> 6;
    const int lane = tid & 63;
    const int l15 = lane & 15;
    const int quad = lane >> 4;

    f32x4 acc[4];
#pragma unroll
    for (int mt = 0; mt < 4; ++mt) acc[mt] = (f32x4){0.f, 0.f, 0.f, 0.f};

#pragma unroll
    for (int ks = 0; ks < 4; ++ks) {
        half8 bfrag = *(const half8*)&Bsl[wave * 16 + l15][quad * 8 + ks * 32];
#pragma unroll
        for (int mt = 0; mt < 4; ++mt) {
            half8 afrag = *(const half8*)&Asl[mt * 16 + l15][quad * 8 + ks * 32];
            acc[mt] = __builtin_amdgcn_mfma_f32_16x16x32_f16(afrag, bfrag, acc[mt], 0, 0, 0);
        }
    }

    // transpose C tile through LDS (reuse Asl) for vectorized stores; row scale + bias here
    const int col = wave * 16 + l15;
    const float bv = bias[n0 + col];
    __syncthreads();
#pragma unroll
    for (int mt = 0; mt < 4; ++mt)
#pragma unroll
        for (int r = 0; r < 4; ++r) {
            int m = m0 + mt * 16 + quad * 4 + r;
            float s = 1.f;
            if (ns) {
                int mm = (m < M) ? m : 0;
                int ar = gidx ? gidx[mm] : mm;
                s = ns[ar];
            }
            Asl[mt * 16 + quad * 4 + r][col] = (_Float16)(acc[mt][r] * s + bv);
        }
    __syncthreads();
    // 64 rows x 8 chunks (64 cols) = 512 units; 16B/lane coalesced
#pragma unroll
    for (int i = 0; i < 2; ++i) {
        int u = i * 256 + tid;
        int r = u >> 3;          // 0..63 row in tile
        int c = u & 7;           // 0..7  8-half chunk within the 64-col tile
        int m = m0 + r;
        if (m < M)
            *(half8*)(C + (size_t)m * N + n0 + c * 8) = *(const half8*)&Asl[r][c * 8];
    }
}

// ---------------- paneled SpMM aggregate + leaky-relu; panel = 32 cols (3.2 MB, L2-resident) ----
// grid (NPOI, 4) x-fastest keeps one panel hot per XCD L2. Writes unnormalized fp16 agg +
// per-(row,panel) sumsq (single writer, no atomics). Norm factored to consumers via ns[].

__global__ __launch_bounds__(64) void spmm_panel_kernel(
    const _Float16* __restrict__ h, const int* __restrict__ offs,
    const unsigned* __restrict__ ew, _Float16* __restrict__ agg_h,
    float* __restrict__ sq4)
{
    const int row = blockIdx.x;
    const int p = blockIdx.y;
    const int lane = threadIdx.x;
    const int col = lane & 31;
    const int par = lane >> 5;      // edge parity: lanes 0-31 even edges, 32-63 odd
    const int beg = offs[row];
    const int end = offs[row + 1];
    float acc = 0.f;
#pragma unroll 4
    for (int e = beg + par; e < end; e += 2) {
        unsigned pe = ew[e];
        HBits cv; cv.u = (unsigned short)(pe & 0xffffu);
        float w = (float)cv.h;
        int d = pe >> 16;
        acc += w * (float)h[(size_t)d * 128 + p * 32 + col];
    }
    acc += __shfl_xor(acc, 32);                    // combine edge parities (same col)
    acc = acc >= 0.f ? acc : 0.01f * acc;          // leaky_relu
    float ss = acc * acc;
#pragma unroll
    for (int o = 1; o < 32; o <<= 1) ss += __shfl_xor(ss, o);
    if (lane < 32) {
        agg_h[(size_t)row * 128 + p * 32 + col] = (_Float16)acc;
        if (lane == 0) sq4[row * 4 + p] = ss;
    }
}

__global__ void ns_kernel(const float* __restrict__ sq4, float* __restrict__ ns) {
    int i = blockIdx.x * blockDim.x + threadIdx.x;
    if (i < NPOI) {
        float ss = sq4[4 * i] + sq4[4 * i + 1] + sq4[4 * i + 2] + sq4[4 * i + 3];
        ns[i] = 1.f / fmaxf(sqrtf(ss), 1e-12f);
    }
}

// ---------------- MFMA attention + mean + out_proj + fused tar gather ----------------

__global__ __launch_bounds__(256) void attn_mfma_kernel(
    const _Float16* __restrict__ qkv, const float* __restrict__ outw,
    const float* __restrict__ outb, const _Float16* __restrict__ agg_h,
    const float* __restrict__ ns, const int* __restrict__ data_poi,
    float* __restrict__ out)
{
    const int b = blockIdx.x;
    const int wave = threadIdx.x >> 6;   // head
    const int lane = threadIdx.x & 63;
    const int l15 = lane & 15;
    const int quad = lane >> 4;
    __shared__ _Float16 pP[NHEADS][64][72];
    __shared__ _Float16 vT[NHEADS][32][72];
    __shared__ float ob[128];
    const _Float16* base = qkv + (size_t)b * SEQL * 384;

    // stage V^T: lane m scatters its V row
    {
        const _Float16* vrow = base + (size_t)lane * 384 + 256 + wave * 32;
        half8 v0 = *(const half8*)(vrow);
        half8 v1 = *(const half8*)(vrow + 8);
        half8 v2 = *(const half8*)(vrow + 16);
        half8 v3 = *(const half8*)(vrow + 24);
#pragma unroll
        for (int j = 0; j < 8; ++j) {
            vT[wave][j][lane]      = v0[j];
            vT[wave][j + 8][lane]  = v1[j];
            vT[wave][j + 16][lane] = v2[j];
            vT[wave][j + 24][lane] = v3[j];
        }
    }

    // Q / K fragments straight from global (A-layout: row=l15, k=quad*8+j)
    half8 qf[4], kf[4];
#pragma unroll
    for (int t = 0; t < 4; ++t) {
        qf[t] = *(const half8*)(base + (size_t)(t * 16 + l15) * 384 + wave * 32 + quad * 8);
        kf[t] = *(const half8*)(base + (size_t)(t * 16 + l15) * 384 + 128 + wave * 32 + quad * 8);
    }

    f32x4 S[4][4];
#pragma unroll
    for (int lt = 0; lt < 4; ++lt)
#pragma unroll
        for (int mt = 0; mt < 4; ++mt) S[lt][mt] = (f32x4){0.f, 0.f, 0.f, 0.f};
#pragma unroll
    for (int lt = 0; lt < 4; ++lt)
#pragma unroll
        for (int mt = 0; mt < 4; ++mt)
            S[lt][mt] = __builtin_amdgcn_mfma_f32_16x16x32_f16(qf[lt], kf[mt], S[lt][mt], 0, 0, 0);

    const float scale = 0.17677669529663687f;  // 1/sqrt(32)
#pragma unroll
    for (int lt = 0; lt < 4; ++lt) {
#pragma unroll
        for (int r = 0; r < 4; ++r) {
            float m0 = -1e30f;
#pragma unroll
            for (int mt = 0; mt < 4; ++mt) {
                S[lt][mt][r] *= scale;
                m0 = fmaxf(m0, S[lt][mt][r]);
            }
#pragma unroll
            for (int o = 1; o < 16; o <<= 1) m0 = fmaxf(m0, __shfl_xor(m0, o));
            float s0 = 0.f;
#pragma unroll
            for (int mt = 0; mt < 4; ++mt) {
                float p = __expf(S[lt][mt][r] - m0);
                S[lt][mt][r] = p;
                s0 += p;
            }
#pragma unroll
            for (int o = 1; o < 16; o <<= 1) s0 += __shfl_xor(s0, o);
            float inv = 1.f / s0;
#pragma unroll
            for (int mt = 0; mt < 4; ++mt)
                pP[wave][lt * 16 + quad * 4 + r][mt * 16 + l15] = (_Float16)(S[lt][mt][r] * inv);
        }
    }
    __syncthreads();

    // O = P V : contraction over m (64) in 2 steps
    f32x4 O[4][2];
#pragma unroll
    for (int lt = 0; lt < 4; ++lt)
#pragma unroll
        for (int jt = 0; jt < 2; ++jt) O[lt][jt] = (f32x4){0.f, 0.f, 0.f, 0.f};
#pragma unroll
    for (int kh = 0; kh < 2; ++kh) {
        half8 vf[2];
#pragma unroll
        for (int jt = 0; jt < 2; ++jt)
            vf[jt] = *(const half8*)&vT[wave][jt * 16 + l15][kh * 32 + quad * 8];
#pragma unroll
        for (int lt = 0; lt < 4; ++lt) {
            half8 pf = *(const half8*)&pP[wave][lt * 16 + l15][kh * 32 + quad * 8];
#pragma unroll
            for (int jt = 0; jt < 2; ++jt)
                O[lt][jt] = __builtin_amdgcn_mfma_f32_16x16x32_f16(pf, vf[jt], O[lt][jt], 0, 0, 0);
        }
    }

    // mean over the 64 query rows -> ob[head*32 + j]
#pragma unroll
    for (int jt = 0; jt < 2; ++jt) {
        float part = 0.f;
#pragma unroll
        for (int lt = 0; lt < 4; ++lt)
#pragma unroll
            for (int r = 0; r < 4; ++r) part += O[lt][jt][r];
        part += __shfl_xor(part, 16);
        part += __shfl_xor(part, 32);
        if (quad == 0) ob[wave * 32 + jt * 16 + l15] = part * (1.f / 64.f);
    }
    __syncthreads();

    int t = threadIdx.x;
    if (t < 128) {
        float val = outb[t];
        const float* wrow = outw + (size_t)t * 128;
#pragma unroll 8
        for (int k4 = 0; k4 < 32; ++k4) {
            float4 wv = *(const float4*)(wrow + k4 * 4);
            val += wv.x * ob[k4 * 4] + wv.y * ob[k4 * 4 + 1]
                 + wv.z * ob[k4 * 4 + 2] + wv.w * ob[k4 * 4 + 3];
        }
        out[(size_t)b * 128 + t] = val;
    } else {
        // fused tar_embed gather: enc = agg_h * ns (normalized on the fly)
        int j = t - 128;
        int r = data_poi[b];
        out[(size_t)(BATCH + b) * 128 + j] = (float)agg_h[(size_t)r * 128 + j] * ns[r];
    }
}

// ---------------- launch ----------------

extern "C" void kernel_launch(void* const* d_in, const int* in_sizes, int n_in,
                              void* d_out, int out_size, void* d_ws, size_t ws_size,
                              hipStream_t stream)
{
    const float* poi      = (const float*)d_in[0];
    const int*   edges    = (const int*)d_in[1];
    const float* dvec     = (const float*)d_in[2];
    const int*   data_poi = (const int*)d_in[3];
    const int*   data_x   = (const int*)d_in[4];
    const float* lin_w    = (const float*)d_in[5];
    const float* lin_b    = (const float*)d_in[6];
    const float* inw      = (const float*)d_in[7];
    const float* inb      = (const float*)d_in[8];
    const float* outw     = (const float*)d_in[9];
    const float* outb     = (const float*)d_in[10];
    const int* e0 = edges;
    const int* e1 = edges + NEDGE;

    char* ws = (char*)d_ws;
    size_t off = 0;
    auto alloc = [&](size_t bytes) -> void* {
        void* p = ws + off;
        off = (off + bytes + 255) & ~(size_t)255;
        return p;
    };
    int*      offs   = (int*)     alloc((NPOI + 1) * 4);
    int*      bsum   = (int*)     alloc(NB * 4);
    int*      bcur   = (int*)     alloc(NB * 4);
    float*    rd     = (float*)   alloc(NPOI * 4);
    float*    sq4    = (float*)   alloc((size_t)NPOI * 4 * 4);
    float*    ns     = (float*)   alloc(NPOI * 4);
    unsigned* ew     = (unsigned*)alloc((size_t)EAUG * 4);
    _Float16* agg_h  = (_Float16*)alloc((size_t)NPOI * 128 * 2);
    _Float16* linw_h = (_Float16*)alloc((size_t)2 * 128 * 128 * 2);
    _Float16* inw_h  = (_Float16*)alloc((size_t)384 * 128 * 2);
    char*     big    = (char*)    alloc(50ull * 1024 * 1024);
    // aliases inside the big region (lifetimes strictly ordered):
    //   poi_h   [ 0, 12.8 MB)  — cvt -> GEMM1
    //   staging [16, 32.1 MB)  — partition -> hist/csr_sort
    //   hbuf    [33, 45.8 MB)  — GEMM1/2 -> spmm panels
    //   qkv_h   [ 0, 25.2 MB)  — qkv GEMM (after all above dead) -> attn
    _Float16* poi_h   = (_Float16*)big;
    u64*      staging = (u64*)(big + 16ull * 1024 * 1024);
    _Float16* hbuf    = (_Float16*)(big + 33ull * 1024 * 1024);
    _Float16* qkv_h   = (_Float16*)big;

    cvt_all_kernel<<<(CVT_TOT + 255) / 256, 256, 0, stream>>>(
        poi, lin_w, inw, poi_h, linw_h, inw_h, bcur);

    partition_kernel<<<P1_BLOCKS, 256, 0, stream>>>(e0, e1, dvec, bcur, staging);
    hist_kernel<<<NB, 256, 0, stream>>>(staging, bcur, rd, bsum);
    csr_sort_kernel<<<NB, 256, 0, stream>>>(staging, bcur, bsum, rd, offs, ew);

    // layer 1
    gemm_mfma_f16<<<dim3(2, (NPOI + 63) / 64), 256, 0, stream>>>(
        poi_h, nullptr, nullptr, linw_h, lin_b, hbuf, NPOI, 128);
    spmm_panel_kernel<<<dim3(NPOI, 4), 64, 0, stream>>>(hbuf, offs, ew, agg_h, sq4);
    ns_kernel<<<(NPOI + 255) / 256, 256, 0, stream>>>(sq4, ns);

    // layer 2 (A-row norm of layer 1 applied in epilogue via ns)
    gemm_mfma_f16<<<dim3(2, (NPOI + 63) / 64), 256, 0, stream>>>(
        agg_h, nullptr, ns, linw_h + 128 * 128, lin_b + 128, hbuf, NPOI, 128);
    spmm_panel_kernel<<<dim3(NPOI, 4), 64, 0, stream>>>(hbuf, offs, ew, agg_h, sq4);
    ns_kernel<<<(NPOI + 255) / 256, 256, 0, stream>>>(sq4, ns);

    // attention (qkv gemm fp16 with row-norm in epilogue -> MFMA attn + mean + out_proj + tar)
    gemm_mfma_f16<<<dim3(6, BATCH * SEQL / 64), 256, 0, stream>>>(
        agg_h, data_x, ns, inw_h, inb, qkv_h, BATCH * SEQL, 384);
    attn_mfma_kernel<<<BATCH, 256, 0, stream>>>(qkv_h, outw, outb, agg_h, ns, data_poi,
                                                (float*)d_out);
}

// Round 12
// 281.243 us; speedup vs baseline: 1.5959x; 1.5959x over previous
//
#include <hip/hip_runtime.h>
#include <hip/hip_fp16.h>

#define NPOI 50000
#define EMB 128
#define NEDGE 800000
#define EAUG (2 * NEDGE + NPOI)
#define BATCH 512
#define SEQL 64
#define NHEADS 4
#define HDIM 32
#define NB 196                              // 256-node buckets
#define P1_BLOCKS ((NEDGE + 2047) / 2048)   // 391
#define SLAB_CAP 10240
#define BUCKET_CAP 10240

typedef _Float16 half8 __attribute__((ext_vector_type(8)));
typedef _Float16 half4 __attribute__((ext_vector_type(4)));
typedef _Float16 half2t __attribute__((ext_vector_type(2)));
typedef float f32x4 __attribute__((ext_vector_type(4)));
typedef unsigned long long u64;

union HBits { _Float16 h; unsigned short u; };

// ---------------- fused fp32 -> fp16 convert (poi, lin_w, in_proj_w) + bcur init ----------------

#define N4_POI (NPOI * 128 / 4)
#define N4_LIN (2 * 128 * 128 / 4)
#define N4_INW (384 * 128 / 4)
#define CVT_TOT (N4_POI + N4_LIN + N4_INW + NB)

__global__ void cvt_all_kernel(const float* __restrict__ poi, const float* __restrict__ linw,
                               const float* __restrict__ inw,
                               _Float16* __restrict__ poi_h, _Float16* __restrict__ linw_h,
                               _Float16* __restrict__ inw_h, int* __restrict__ bcur) {
    int i = blockIdx.x * blockDim.x + threadIdx.x;
    const float* src; _Float16* dst; int j = i;
    if (i < N4_POI) { src = poi; dst = poi_h; }
    else if (i < N4_POI + N4_LIN) { j = i - N4_POI; src = linw; dst = linw_h; }
    else if (i < N4_POI + N4_LIN + N4_INW) { j = i - N4_POI - N4_LIN; src = inw; dst = inw_h; }
    else if (i < CVT_TOT) { int b = i - (N4_POI + N4_LIN + N4_INW); bcur[b] = b * SLAB_CAP; return; }
    else return;
    float4 v = ((const float4*)src)[j];
    half4 h = { (_Float16)v.x, (_Float16)v.y, (_Float16)v.z, (_Float16)v.w };
    ((half4*)dst)[j] = h;
}

// ---------------- phase 1: LDS-buffered multisplit into static per-bucket slabs ----------------

__global__ __launch_bounds__(256) void partition_kernel(
    const int* __restrict__ e0, const int* __restrict__ e1,
    const float* __restrict__ dv, int* __restrict__ bcur,
    u64* __restrict__ staging)
{
    __shared__ u64 stg[4096];
    __shared__ int lh[NB], lbase[NB], gb[NB];
    __shared__ int sc[256];
    const int t = threadIdx.x;
    const int blockBase = blockIdx.x * 2048;
    for (int j = t; j < NB; j += 256) lh[j] = 0;
    __syncthreads();

    u64 vals[16];
    unsigned br[16];
#pragma unroll
    for (int i = 0; i < 8; ++i) {
        br[2 * i] = 0xFFFFFFFFu;
        br[2 * i + 1] = 0xFFFFFFFFu;
        int g = blockBase + i * 256 + t;
        if (g < NEDGE) {
            int s = e0[g], d = e1[g];
            unsigned db = __float_as_uint(dv[g]);
            vals[2 * i]     = ((u64)s << 48) | ((u64)d << 32) | db;
            vals[2 * i + 1] = ((u64)d << 48) | ((u64)s << 32) | db;
            int bs = s >> 8, bd = d >> 8;
            int rs = atomicAdd(&lh[bs], 1);
            int rd_ = atomicAdd(&lh[bd], 1);
            br[2 * i]     = ((unsigned)bs << 16) | (unsigned)rs;
            br[2 * i + 1] = ((unsigned)bd << 16) | (unsigned)rd_;
        }
    }
    __syncthreads();
    sc[t] = (t < NB) ? lh[t] : 0;
    __syncthreads();
    for (int o = 1; o < 256; o <<= 1) {
        int u = (t >= o) ? sc[t - o] : 0;
        __syncthreads();
        sc[t] += u;
        __syncthreads();
    }
    if (t < NB) {
        lbase[t] = sc[t] - lh[t];
        gb[t] = (lh[t] > 0) ? atomicAdd(&bcur[t], lh[t]) : 0;
    }
    __syncthreads();
#pragma unroll
    for (int i = 0; i < 16; ++i) {
        if (br[i] != 0xFFFFFFFFu) {
            int b = br[i] >> 16, r = br[i] & 0xFFFF;
            stg[lbase[b] + r] = vals[i];
        }
    }
    __syncthreads();
    const int total = sc[255];
    for (int j = t; j < total; j += 256) {
        u64 v = stg[j];
        int b = (int)(v >> 56);
        staging[(size_t)gb[b] + (unsigned)(j - lbase[b])] = v;
    }
}

// ---------------- per-bucket histogram -> rd = rsqrt(deg), bsum ----------------

__global__ __launch_bounds__(256) void hist_kernel(const u64* __restrict__ staging,
                                                   const int* __restrict__ bcur,
                                                   float* __restrict__ rd,
                                                   int* __restrict__ bsum) {
    __shared__ int cnt[256];
    __shared__ int red[256];
    const int b = blockIdx.x, t = threadIdx.x;
    cnt[t] = 0;
    __syncthreads();
    const int base = b * SLAB_CAP;
    const int n = bcur[b] - base;
    for (int j = t; j < n; j += 256)
        atomicAdd(&cnt[(int)(staging[base + j] >> 48) & 255], 1);
    __syncthreads();
    int node = b * 256 + t;
    int rowsz = 0;
    if (node < NPOI) {
        rowsz = cnt[t] + 1;   // + self loop
        rd[node] = rsqrtf((float)rowsz);
    }
    red[t] = rowsz;
    __syncthreads();
    for (int o = 128; o > 0; o >>= 1) {
        if (t < o) red[t] += red[t + o];
        __syncthreads();
    }
    if (t == 0) bsum[b] = red[0];
}

// ---------------- phase 2: per-bucket counting sort + weights + offs -> packed CSR ----------------

__global__ __launch_bounds__(256) void csr_sort_kernel(
    const u64* __restrict__ staging, const int* __restrict__ bcur,
    const int* __restrict__ bsum, const float* __restrict__ rd,
    int* __restrict__ offs, unsigned* __restrict__ ew)
{
    const int k = blockIdx.x;
    const int node0 = k * 256;
    __shared__ unsigned outb[BUCKET_CAP];
    __shared__ int cnt[256], base2[256];
    __shared__ float rdl[256];
    __shared__ int bb_sh;
    const int t = threadIdx.x;
    const int node = node0 + t;
    cnt[t] = 0;
    rdl[t] = (node < NPOI) ? rd[node] : 0.f;
    // bucket base = prefix sum of bsum[0..k-1]
    {
        int partial = 0;
        for (int j = t; j < k; j += 256) partial += bsum[j];
        base2[t] = partial;
        __syncthreads();
        for (int o = 128; o > 0; o >>= 1) {
            if (t < o) base2[t] += base2[t + o];
            __syncthreads();
        }
        if (t == 0) bb_sh = base2[0];
        __syncthreads();
    }
    const int bucketbase = bb_sh;
    __syncthreads();
    const int sb = k * SLAB_CAP;
    const int n = bcur[k] - sb;
    for (int j = t; j < n; j += 256)
        atomicAdd(&cnt[(int)(staging[sb + j] >> 48) & 255], 1);
    __syncthreads();
    int rowsz = (node < NPOI) ? cnt[t] + 1 : 0;
    base2[t] = rowsz;
    __syncthreads();
    for (int o = 1; o < 256; o <<= 1) {
        int u = (t >= o) ? base2[t - o] : 0;
        __syncthreads();
        base2[t] += u;
        __syncthreads();
    }
    int myexc = base2[t] - rowsz;
    __syncthreads();
    base2[t] = myexc;
    cnt[t] = 0;
    if (node < NPOI) {
        offs[node] = bucketbase + myexc;
        if (node == NPOI - 1) offs[NPOI] = bucketbase + myexc + rowsz;
    }
    __syncthreads();
    for (int j = t; j < n; j += 256) {
        u64 e = staging[sb + j];
        int sl = (int)(e >> 48) & 255;
        int d = (int)(e >> 32) & 0xFFFF;
        float dist = __uint_as_float((unsigned)e);
        float w = rdl[sl] * rd[d] * expf(-dist * dist);
        HBits cv; cv.h = (_Float16)w;
        int r = atomicAdd(&cnt[sl], 1);
        outb[base2[sl] + r] = ((unsigned)d << 16) | cv.u;
    }
    __syncthreads();
    if (node < NPOI) {   // self loop in last slot of the row
        float w = rdl[t] * rdl[t];
        HBits cv; cv.h = (_Float16)w;
        outb[base2[t] + cnt[t]] = ((unsigned)node << 16) | cv.u;
    }
    __syncthreads();
    const int ntot = (node0 + 256 < NPOI ? n + 256 : n + (NPOI - node0));
    for (int j = t; j < ntot; j += 256) ew[bucketbase + j] = outb[j];   // coalesced
}

// ---------------- fp16 MFMA GEMM: C[M,N] = A(gathered)[M,128] @ B[N,128]^T + bias ----------------
// epilogue: C tile transposed through LDS -> 16B/lane coalesced fp16 stores

__global__ __launch_bounds__(256) void gemm_mfma_f16(
    const _Float16* __restrict__ A, const int* __restrict__ gidx,
    const _Float16* __restrict__ B, const float* __restrict__ bias,
    _Float16* __restrict__ C, int M, int N)
{
    __shared__ _Float16 Asl[64][136];
    __shared__ _Float16 Bsl[64][136];
    const int tid = threadIdx.x;
    const int n0 = blockIdx.x * 64;
    const int m0 = blockIdx.y * 64;

#pragma unroll
    for (int i = 0; i < 4; ++i) {
        int u = i * 256 + tid;
        int r = u >> 4;
        int c = u & 15;
        int row = m0 + r;
        int ar = (row < M) ? (gidx ? gidx[row] : row) : 0;
        *(float4*)&Asl[r][c * 8] = *(const float4*)(A + (size_t)ar * 128 + c * 8);
        *(float4*)&Bsl[r][c * 8] = *(const float4*)(B + (size_t)(n0 + r) * 128 + c * 8);
    }
    __syncthreads();

    const int wave = tid >> 6;
    const int lane = tid & 63;
    const int l15 = lane & 15;
    const int quad = lane >> 4;

    f32x4 acc[4];
#pragma unroll
    for (int mt = 0; mt < 4; ++mt) acc[mt] = (f32x4){0.f, 0.f, 0.f, 0.f};

#pragma unroll
    for (int ks = 0; ks < 4; ++ks) {
        half8 bfrag = *(const half8*)&Bsl[wave * 16 + l15][quad * 8 + ks * 32];
#pragma unroll
        for (int mt = 0; mt < 4; ++mt) {
            half8 afrag = *(const half8*)&Asl[mt * 16 + l15][quad * 8 + ks * 32];
            acc[mt] = __builtin_amdgcn_mfma_f32_16x16x32_f16(afrag, bfrag, acc[mt], 0, 0, 0);
        }
    }

    // transpose C tile through LDS (reuse Asl) for vectorized stores
    const int col = wave * 16 + l15;
    const float bv = bias[n0 + col];
    __syncthreads();
#pragma unroll
    for (int mt = 0; mt < 4; ++mt)
#pragma unroll
        for (int r = 0; r < 4; ++r)
            Asl[mt * 16 + quad * 4 + r][col] = (_Float16)(acc[mt][r] + bv);
    __syncthreads();
    // 64 rows x 8 chunks (64 cols) = 512 units; 16B/lane coalesced
#pragma unroll
    for (int i = 0; i < 2; ++i) {
        int u = i * 256 + tid;
        int r = u >> 3;          // 0..63 row in tile
        int c = u & 7;           // 0..7  8-half chunk within the 64-col tile
        int m = m0 + r;
        if (m < M)
            *(half8*)(C + (size_t)m * N + n0 + c * 8) = *(const half8*)&Asl[r][c * 8];
    }
}

// ---------------- CSR aggregate + leaky-relu + L2 normalize (full row, fp16 out only) ----------

__global__ __launch_bounds__(64) void aggregate_kernel(
    const _Float16* __restrict__ h, const int* __restrict__ offs,
    const unsigned* __restrict__ ew, _Float16* __restrict__ enc_h)
{
    const int row = blockIdx.x;
    const int lane = threadIdx.x;
    const int beg = offs[row];
    const int end = offs[row + 1];
    float ax = 0.f, ay = 0.f;
#pragma unroll 8
    for (int e = beg; e < end; ++e) {
        unsigned p = ew[e];
        HBits cv; cv.u = (unsigned short)(p & 0xffffu);
        float w = (float)cv.h;
        int d = p >> 16;
        half2t hv = *(const half2t*)(h + (size_t)d * 128 + lane * 2);
        ax += w * (float)hv[0];
        ay += w * (float)hv[1];
    }
    ax = ax >= 0.f ? ax : 0.01f * ax;
    ay = ay >= 0.f ? ay : 0.01f * ay;
    float ss = ax * ax + ay * ay;
#pragma unroll
    for (int o = 32; o > 0; o >>= 1) ss += __shfl_xor(ss, o);
    float inv = 1.f / fmaxf(sqrtf(ss), 1e-12f);
    half2t hv = { (_Float16)(ax * inv), (_Float16)(ay * inv) };
    *(half2t*)(enc_h + (size_t)row * 128 + lane * 2) = hv;
}

// ---------------- MFMA attention + mean + out_proj + fused tar gather ----------------

__global__ __launch_bounds__(256) void attn_mfma_kernel(
    const _Float16* __restrict__ qkv, const float* __restrict__ outw,
    const float* __restrict__ outb, const _Float16* __restrict__ enc_h,
    const int* __restrict__ data_poi, float* __restrict__ out)
{
    const int b = blockIdx.x;
    const int wave = threadIdx.x >> 6;   // head
    const int lane = threadIdx.x & 63;
    const int l15 = lane & 15;
    const int quad = lane >> 4;
    __shared__ _Float16 pP[NHEADS][64][72];
    __shared__ _Float16 vT[NHEADS][32][72];
    __shared__ float ob[128];
    const _Float16* base = qkv + (size_t)b * SEQL * 384;

    // stage V^T: lane m scatters its V row
    {
        const _Float16* vrow = base + (size_t)lane * 384 + 256 + wave * 32;
        half8 v0 = *(const half8*)(vrow);
        half8 v1 = *(const half8*)(vrow + 8);
        half8 v2 = *(const half8*)(vrow + 16);
        half8 v3 = *(const half8*)(vrow + 24);
#pragma unroll
        for (int j = 0; j < 8; ++j) {
            vT[wave][j][lane]      = v0[j];
            vT[wave][j + 8][lane]  = v1[j];
            vT[wave][j + 16][lane] = v2[j];
            vT[wave][j + 24][lane] = v3[j];
        }
    }

    // Q / K fragments straight from global (A-layout: row=l15, k=quad*8+j)
    half8 qf[4], kf[4];
#pragma unroll
    for (int t = 0; t < 4; ++t) {
        qf[t] = *(const half8*)(base + (size_t)(t * 16 + l15) * 384 + wave * 32 + quad * 8);
        kf[t] = *(const half8*)(base + (size_t)(t * 16 + l15) * 384 + 128 + wave * 32 + quad * 8);
    }

    f32x4 S[4][4];
#pragma unroll
    for (int lt = 0; lt < 4; ++lt)
#pragma unroll
        for (int mt = 0; mt < 4; ++mt) S[lt][mt] = (f32x4){0.f, 0.f, 0.f, 0.f};
#pragma unroll
    for (int lt = 0; lt < 4; ++lt)
#pragma unroll
        for (int mt = 0; mt < 4; ++mt)
            S[lt][mt] = __builtin_amdgcn_mfma_f32_16x16x32_f16(qf[lt], kf[mt], S[lt][mt], 0, 0, 0);

    const float scale = 0.17677669529663687f;  // 1/sqrt(32)
#pragma unroll
    for (int lt = 0; lt < 4; ++lt) {
#pragma unroll
        for (int r = 0; r < 4; ++r) {
            float m0 = -1e30f;
#pragma unroll
            for (int mt = 0; mt < 4; ++mt) {
                S[lt][mt][r] *= scale;
                m0 = fmaxf(m0, S[lt][mt][r]);
            }
#pragma unroll
            for (int o = 1; o < 16; o <<= 1) m0 = fmaxf(m0, __shfl_xor(m0, o));
            float s0 = 0.f;
#pragma unroll
            for (int mt = 0; mt < 4; ++mt) {
                float p = __expf(S[lt][mt][r] - m0);
                S[lt][mt][r] = p;
                s0 += p;
            }
#pragma unroll
            for (int o = 1; o < 16; o <<= 1) s0 += __shfl_xor(s0, o);
            float inv = 1.f / s0;
#pragma unroll
            for (int mt = 0; mt < 4; ++mt)
                pP[wave][lt * 16 + quad * 4 + r][mt * 16 + l15] = (_Float16)(S[lt][mt][r] * inv);
        }
    }
    __syncthreads();

    // O = P V : contraction over m (64) in 2 steps
    f32x4 O[4][2];
#pragma unroll
    for (int lt = 0; lt < 4; ++lt)
#pragma unroll
        for (int jt = 0; jt < 2; ++jt) O[lt][jt] = (f32x4){0.f, 0.f, 0.f, 0.f};
#pragma unroll
    for (int kh = 0; kh < 2; ++kh) {
        half8 vf[2];
#pragma unroll
        for (int jt = 0; jt < 2; ++jt)
            vf[jt] = *(const half8*)&vT[wave][jt * 16 + l15][kh * 32 + quad * 8];
#pragma unroll
        for (int lt = 0; lt < 4; ++lt) {
            half8 pf = *(const half8*)&pP[wave][lt * 16 + l15][kh * 32 + quad * 8];
#pragma unroll
            for (int jt = 0; jt < 2; ++jt)
                O[lt][jt] = __builtin_amdgcn_mfma_f32_16x16x32_f16(pf, vf[jt], O[lt][jt], 0, 0, 0);
        }
    }

    // mean over the 64 query rows -> ob[head*32 + j]
#pragma unroll
    for (int jt = 0; jt < 2; ++jt) {
        float part = 0.f;
#pragma unroll
        for (int lt = 0; lt < 4; ++lt)
#pragma unroll
            for (int r = 0; r < 4; ++r) part += O[lt][jt][r];
        part += __shfl_xor(part, 16);
        part += __shfl_xor(part, 32);
        if (quad == 0) ob[wave * 32 + jt * 16 + l15] = part * (1.f / 64.f);
    }
    __syncthreads();

    int t = threadIdx.x;
    if (t < 128) {
        float val = outb[t];
        const float* wrow = outw + (size_t)t * 128;
#pragma unroll 8
        for (int k4 = 0; k4 < 32; ++k4) {
            float4 wv = *(const float4*)(wrow + k4 * 4);
            val += wv.x * ob[k4 * 4] + wv.y * ob[k4 * 4 + 1]
                 + wv.z * ob[k4 * 4 + 2] + wv.w * ob[k4 * 4 + 3];
        }
        out[(size_t)b * 128 + t] = val;
    } else {
        // fused tar_embed gather (fp16 enc)
        int j = t - 128;
        out[(size_t)(BATCH + b) * 128 + j] = (float)enc_h[(size_t)data_poi[b] * 128 + j];
    }
}

// ---------------- launch ----------------

extern "C" void kernel_launch(void* const* d_in, const int* in_sizes, int n_in,
                              void* d_out, int out_size, void* d_ws, size_t ws_size,
                              hipStream_t stream)
{
    const float* poi      = (const float*)d_in[0];
    const int*   edges    = (const int*)d_in[1];
    const float* dvec     = (const float*)d_in[2];
    const int*   data_poi = (const int*)d_in[3];
    const int*   data_x   = (const int*)d_in[4];
    const float* lin_w    = (const float*)d_in[5];
    const float* lin_b    = (const float*)d_in[6];
    const float* inw      = (const float*)d_in[7];
    const float* inb      = (const float*)d_in[8];
    const float* outw     = (const float*)d_in[9];
    const float* outb     = (const float*)d_in[10];
    const int* e0 = edges;
    const int* e1 = edges + NEDGE;

    char* ws = (char*)d_ws;
    size_t off = 0;
    auto alloc = [&](size_t bytes) -> void* {
        void* p = ws + off;
        off = (off + bytes + 255) & ~(size_t)255;
        return p;
    };
    int*      offs   = (int*)     alloc((NPOI + 1) * 4);
    int*      bsum   = (int*)     alloc(NB * 4);
    int*      bcur   = (int*)     alloc(NB * 4);
    float*    rd     = (float*)   alloc(NPOI * 4);
    unsigned* ew     = (unsigned*)alloc((size_t)EAUG * 4);
    _Float16* enc_h  = (_Float16*)alloc((size_t)NPOI * 128 * 2);
    _Float16* linw_h = (_Float16*)alloc((size_t)2 * 128 * 128 * 2);
    _Float16* inw_h  = (_Float16*)alloc((size_t)384 * 128 * 2);
    char*     big    = (char*)    alloc(50ull * 1024 * 1024);
    // aliases inside the big region (lifetimes strictly ordered):
    //   poi_h   [ 0, 12.8 MB)  — cvt -> GEMM1
    //   staging [16, 32.1 MB)  — partition -> hist/csr_sort
    //   hbuf    [33, 45.8 MB)  — GEMM1/2 -> aggregate
    //   qkv_h   [ 0, 25.2 MB)  — qkv GEMM (after all above dead) -> attn
    _Float16* poi_h   = (_Float16*)big;
    u64*      staging = (u64*)(big + 16ull * 1024 * 1024);
    _Float16* hbuf    = (_Float16*)(big + 33ull * 1024 * 1024);
    _Float16* qkv_h   = (_Float16*)big;

    cvt_all_kernel<<<(CVT_TOT + 255) / 256, 256, 0, stream>>>(
        poi, lin_w, inw, poi_h, linw_h, inw_h, bcur);

    partition_kernel<<<P1_BLOCKS, 256, 0, stream>>>(e0, e1, dvec, bcur, staging);
    hist_kernel<<<NB, 256, 0, stream>>>(staging, bcur, rd, bsum);
    csr_sort_kernel<<<NB, 256, 0, stream>>>(staging, bcur, bsum, rd, offs, ew);

    // 2 graph-conv layers
    gemm_mfma_f16<<<dim3(2, (NPOI + 63) / 64), 256, 0, stream>>>(
        poi_h, nullptr, linw_h, lin_b, hbuf, NPOI, 128);
    aggregate_kernel<<<NPOI, 64, 0, stream>>>(hbuf, offs, ew, enc_h);
    gemm_mfma_f16<<<dim3(2, (NPOI + 63) / 64), 256, 0, stream>>>(
        enc_h, nullptr, linw_h + 128 * 128, lin_b + 128, hbuf, NPOI, 128);
    aggregate_kernel<<<NPOI, 64, 0, stream>>>(hbuf, offs, ew, enc_h);

    // attention (qkv gemm fp16 -> MFMA attn + mean + out_proj + tar -> d_out)
    gemm_mfma_f16<<<dim3(6, BATCH * SEQL / 64), 256, 0, stream>>>(
        enc_h, data_x, inw_h, inb, qkv_h, BATCH * SEQL, 384);
    attn_mfma_kernel<<<BATCH, 256, 0, stream>>>(qkv_h, outw, outb, enc_h, data_poi,
                                                (float*)d_out);
}